// Round 3
// baseline (477.104 us; speedup 1.0000x reference)
//
#include <hip/hip_runtime.h>

#define D 64
#define LDA2 136  // bf16 row stride for 128-wide A2 tile: 272 B = 17*16

typedef __attribute__((ext_vector_type(8))) short short8;
typedef __attribute__((ext_vector_type(4))) float f32x4;

__device__ __forceinline__ ushort f2b(float f) {
    union { float f; unsigned u; } x; x.f = f;
    unsigned r = x.u + 0x7FFFu + ((x.u >> 16) & 1u);   // RNE to bf16
    return (ushort)(r >> 16);
}
__device__ __forceinline__ float b2f(ushort u) {
    union { float f; unsigned u; } x; x.u = ((unsigned)u) << 16;
    return x.f;
}
__device__ __forceinline__ short8 pack8(float4 a, float4 b) {
    short8 r;
    r[0] = (short)f2b(a.x); r[1] = (short)f2b(a.y); r[2] = (short)f2b(a.z); r[3] = (short)f2b(a.w);
    r[4] = (short)f2b(b.x); r[5] = (short)f2b(b.y); r[6] = (short)f2b(b.z); r[7] = (short)f2b(b.w);
    return r;
}
// HW packed bf16 atomic add (2 adjacent bf16 per dword). Inline asm to avoid
// builtin-availability churn across ROCm versions.
__device__ __forceinline__ void atomic_pk_add_bf16(ushort* p, float lo, float hi) {
    unsigned d = ((unsigned)f2b(hi) << 16) | (unsigned)f2b(lo);
    asm volatile("global_atomic_pk_add_bf16 %0, %1, off" :: "v"(p), "v"(d) : "memory");
}

// ---------------------------------------------------------------------------
// Kernel 0: one-block setup — bf16 fragment-layout weight tables + fused bias.
// Wt_e[n*64+k]  = bf16(W_edge[k][n]);  Wt_d[n*128+k] = bf16(W_dense[k][n]).
// ---------------------------------------------------------------------------
__global__ __launch_bounds__(256) void setup_kernel(
    const float* __restrict__ W_edge, const float* __restrict__ W_dense,
    const float* __restrict__ b_dense, const float* __restrict__ bias_edge,
    ushort* __restrict__ Wt_e, ushort* __restrict__ Wt_d, float* __restrict__ bias2)
{
    const int tid = threadIdx.x;
    for (int i = tid; i < 64 * 64; i += 256) {
        int n = i >> 6, k = i & 63;
        Wt_e[i] = f2b(W_edge[k * 64 + n]);
    }
    for (int i = tid; i < 64 * 128; i += 256) {
        int n = i >> 7, k = i & 127;
        Wt_d[i] = f2b(W_dense[k * 64 + n]);
    }
    if (tid < 64) bias2[tid] = b_dense[tid] + bias_edge[tid];
}

// ---------------------------------------------------------------------------
// Kernel 1: nf_out = relu(nf @ W_node + bias_node); also bf16 shadow copy.
// ---------------------------------------------------------------------------
__global__ __launch_bounds__(256) void node_proj_kernel(
    const float* __restrict__ nf, const float* __restrict__ W,
    const float* __restrict__ bias, float* __restrict__ out,
    ushort* __restrict__ out_b, int N)
{
    constexpr int ROWS = 16;
    __shared__ float Ws[D * D];
    __shared__ float As[ROWS * D];
    const int tid = threadIdx.x;
    const long row0 = (long)blockIdx.x * ROWS;

    #pragma unroll
    for (int i = tid; i < D * D / 4; i += 256)
        ((float4*)Ws)[i] = ((const float4*)W)[i];
    {
        int i = tid;  // ROWS*D/4 == 256
        long r = row0 + (i * 4) / D;
        ((float4*)As)[i] = (r < N) ? ((const float4*)nf)[row0 * D / 4 + i]
                                   : make_float4(0.f, 0.f, 0.f, 0.f);
    }
    __syncthreads();

    const int c = tid & 63;
    const float b = bias[c];
    for (int rr = tid >> 6; rr < ROWS; rr += 4) {
        float acc = 0.f;
        #pragma unroll
        for (int k = 0; k < D; ++k)
            acc = fmaf(As[rr * D + k], Ws[k * D + c], acc);
        long r = row0 + rr;
        if (r < N) {
            float v = fmaxf(acc + b, 0.f);
            out[r * D + c] = v;
            out_b[r * D + c] = f2b(v);
        }
    }
}

// ---------------------------------------------------------------------------
// Kernel 2: ef_h = ef @ W_edge via MFMA (global->reg, no LDS);
// packed-bf16 atomic scatter into nb_sum[dst]; deg count.
// ---------------------------------------------------------------------------
__global__ __launch_bounds__(256) void edge_proj_accum_kernel(
    const float* __restrict__ ef, const int* __restrict__ dst,
    const ushort* __restrict__ Wt, ushort* __restrict__ nb_sum,
    float* __restrict__ deg, int E)
{
    const int tid = threadIdx.x;
    const long row0 = (long)blockIdx.x * 64;

    if (tid < 64) {
        long er = row0 + tid;
        if (er < E) atomicAdd(deg + dst[er], 1.0f);
    }

    const int w = tid >> 6, lane = tid & 63;
    const int lr = lane & 15, g = lane >> 4;
    const int arow = 16 * w + lr;
    long era = row0 + arow; if (era >= E) era = E - 1;

    const float4* ap = (const float4*)(ef + era * D);
    float4 v0 = ap[2 * g], v1 = ap[2 * g + 1];          // k = 8g..8g+7
    float4 v2 = ap[8 + 2 * g], v3 = ap[8 + 2 * g + 1];  // k = 32+8g..
    short8 a0 = pack8(v0, v1), a1 = pack8(v2, v3);

    f32x4 acc[4];
    #pragma unroll
    for (int t = 0; t < 4; ++t) {
        f32x4 z = {0.f, 0.f, 0.f, 0.f};
        short8 b0 = *(const short8*)&Wt[(16 * t + lr) * 64 + 8 * g];
        short8 b1 = *(const short8*)&Wt[(16 * t + lr) * 64 + 32 + 8 * g];
        z = __builtin_amdgcn_mfma_f32_16x16x32_bf16(a0, b0, z, 0, 0, 0);
        z = __builtin_amdgcn_mfma_f32_16x16x32_bf16(a1, b1, z, 0, 0, 0);
        acc[t] = z;
    }

    // Packed scatter: lane pair (lr, lr^1) covers cols (c0, c0+1).
    // Even lanes emit rows reg 0,1; odd lanes rows reg 2,3.
    const bool odd = lane & 1;
    const int rb = 16 * w + 4 * g + (odd ? 2 : 0);
    long e0 = row0 + rb, e1 = row0 + rb + 1;
    int dv0 = (e0 < E) ? dst[e0] : -1;
    int dv1 = (e1 < E) ? dst[e1] : -1;
    #pragma unroll
    for (int t = 0; t < 4; ++t) {
        float p0 = __shfl_xor(acc[t][0], 1, 64);
        float p1 = __shfl_xor(acc[t][1], 1, 64);
        float p2 = __shfl_xor(acc[t][2], 1, 64);
        float p3 = __shfl_xor(acc[t][3], 1, 64);
        float lo0, hi0, lo1, hi1;
        if (odd) { lo0 = p2; hi0 = acc[t][2]; lo1 = p3; hi1 = acc[t][3]; }
        else     { lo0 = acc[t][0]; hi0 = p0; lo1 = acc[t][1]; hi1 = p1; }
        int cbase = 16 * t + (lr & ~1);
        if (dv0 >= 0) atomic_pk_add_bf16(nb_sum + (long)dv0 * D + cbase, lo0, hi0);
        if (dv1 >= 0) atomic_pk_add_bf16(nb_sum + (long)dv1 * D + cbase, lo1, hi1);
    }
}

// ---------------------------------------------------------------------------
// Kernel 3: nb_b = bf16( nb_sum / max(deg,1) ), vectorized 8 elems/thread.
// ---------------------------------------------------------------------------
__global__ __launch_bounds__(256) void finalize_nb_kernel(
    const ushort* __restrict__ nb_sum, const float* __restrict__ deg,
    ushort* __restrict__ nb_b, long n_vec8)
{
    long i = (long)blockIdx.x * 256 + threadIdx.x;
    if (i >= n_vec8) return;
    float inv = 1.0f / fmaxf(deg[i >> 3], 1.0f);
    short8 x = ((const short8*)nb_sum)[i];
    short8 r;
    #pragma unroll
    for (int j = 0; j < 8; ++j)
        r[j] = (short)f2b(b2f((ushort)x[j]) * inv);
    ((short8*)nb_b)[i] = r;
}

// ---------------------------------------------------------------------------
// Kernel 4: ef_h (MFMA, global->reg) ; A2 = bf16 concat(ef_h + nb_b[dst],
// 0.5*(nf_b[src]+nf_b[dst])) in LDS; ef_out = relu(A2 @ W_dense + bias2).
// LDS = 17.4 KB only.
// ---------------------------------------------------------------------------
__global__ __launch_bounds__(256, 4) void edge_out_kernel(
    const float* __restrict__ ef, const int* __restrict__ src,
    const int* __restrict__ dst, const ushort* __restrict__ Wt_e,
    const ushort* __restrict__ Wt_d, const ushort* __restrict__ nb_b,
    const ushort* __restrict__ nf_b, const float* __restrict__ bias2,
    float* __restrict__ out, int E)
{
    __shared__ ushort A2[64 * LDA2];   // 17408 B
    const int tid = threadIdx.x;
    const long row0 = (long)blockIdx.x * 64;

    {   // prestage A2: 4 threads per edge
        int e = tid >> 2, q = tid & 3;
        long er = row0 + e; if (er >= E) er = E - 1;
        if (q < 2) {                   // cols 0..63 <- nb_b[dst] (bf16 copy)
            int dv = dst[er];
            const short8* sp = (const short8*)(nb_b + (long)dv * D + q * 32);
            short8 x0 = sp[0], x1 = sp[1], x2 = sp[2], x3 = sp[3];
            short8* dp = (short8*)&A2[e * LDA2 + q * 32];
            dp[0] = x0; dp[1] = x1; dp[2] = x2; dp[3] = x3;
        } else {                       // cols 64..127 <- 0.5*(nf_b[src]+nf_b[dst])
            int c0 = (q - 2) * 32;
            int sv = src[er], dv = dst[er];
            const short8* ap8 = (const short8*)(nf_b + (long)sv * D + c0);
            const short8* bp8 = (const short8*)(nf_b + (long)dv * D + c0);
            short8* dp8 = (short8*)&A2[e * LDA2 + 64 + c0];
            #pragma unroll
            for (int h = 0; h < 4; ++h) {
                short8 xa = ap8[h], xb = bp8[h];
                short8 r;
                #pragma unroll
                for (int j = 0; j < 8; ++j)
                    r[j] = (short)f2b(0.5f * (b2f((ushort)xa[j]) + b2f((ushort)xb[j])));
                dp8[h] = r;
            }
        }
    }

    const int w = tid >> 6, lane = tid & 63;
    const int lr = lane & 15, g = lane >> 4;
    const int arow = 16 * w + lr;
    long era = row0 + arow; if (era >= E) era = E - 1;

    // GEMM1: ef_h fragments from global
    const float4* ap = (const float4*)(ef + era * D);
    float4 v0 = ap[2 * g], v1 = ap[2 * g + 1];
    float4 v2 = ap[8 + 2 * g], v3 = ap[8 + 2 * g + 1];
    short8 a0 = pack8(v0, v1), a1 = pack8(v2, v3);
    f32x4 acc[4];
    #pragma unroll
    for (int t = 0; t < 4; ++t) {
        f32x4 z = {0.f, 0.f, 0.f, 0.f};
        short8 b0 = *(const short8*)&Wt_e[(16 * t + lr) * 64 + 8 * g];
        short8 b1 = *(const short8*)&Wt_e[(16 * t + lr) * 64 + 32 + 8 * g];
        z = __builtin_amdgcn_mfma_f32_16x16x32_bf16(a0, b0, z, 0, 0, 0);
        z = __builtin_amdgcn_mfma_f32_16x16x32_bf16(a1, b1, z, 0, 0, 0);
        acc[t] = z;
    }
    __syncthreads();

    // epilogue1: A2[r][c] += ef_h (bf16 RMW; each element owned by one lane)
    #pragma unroll
    for (int t = 0; t < 4; ++t) {
        int c = 16 * t + lr;
        #pragma unroll
        for (int reg = 0; reg < 4; ++reg) {
            int r = 16 * w + 4 * g + reg;
            int i = r * LDA2 + c;
            A2[i] = f2b(b2f(A2[i]) + acc[t][reg]);
        }
    }
    __syncthreads();

    // GEMM2: [64,128] @ [128,64], B from global table (L1-resident)
    f32x4 acc2[4];
    #pragma unroll
    for (int t = 0; t < 4; ++t) { f32x4 z = {0.f, 0.f, 0.f, 0.f}; acc2[t] = z; }
    #pragma unroll
    for (int ks = 0; ks < 4; ++ks) {
        short8 a = *(const short8*)&A2[arow * LDA2 + 32 * ks + 8 * g];
        #pragma unroll
        for (int t = 0; t < 4; ++t) {
            short8 b = *(const short8*)&Wt_d[(16 * t + lr) * 128 + 32 * ks + 8 * g];
            acc2[t] = __builtin_amdgcn_mfma_f32_16x16x32_bf16(a, b, acc2[t], 0, 0, 0);
        }
    }
    // epilogue2: bias + relu + store
    #pragma unroll
    for (int t = 0; t < 4; ++t) {
        int c = 16 * t + lr;
        float bsum = bias2[c];
        #pragma unroll
        for (int reg = 0; reg < 4; ++reg) {
            long r = row0 + 16 * w + 4 * g + reg;
            if (r < E) out[r * D + c] = fmaxf(acc2[t][reg] + bsum, 0.f);
        }
    }
}

// ---------------------------------------------------------------------------
extern "C" void kernel_launch(void* const* d_in, const int* in_sizes, int n_in,
                              void* d_out, int out_size, void* d_ws, size_t ws_size,
                              hipStream_t stream) {
    const float* nf        = (const float*)d_in[0];
    const float* ef        = (const float*)d_in[1];
    const int*   src       = (const int*)d_in[2];
    const int*   dst       = (const int*)d_in[3];
    const float* W_node    = (const float*)d_in[4];
    const float* W_edge    = (const float*)d_in[5];
    const float* bias_node = (const float*)d_in[6];
    const float* bias_edge = (const float*)d_in[7];
    const float* W_dense   = (const float*)d_in[8];
    const float* b_dense   = (const float*)d_in[9];

    const int N = in_sizes[0] / D;
    const int E = in_sizes[1] / D;

    float*  nf_out = (float*)d_out;
    float*  ef_out = (float*)d_out + (size_t)N * D;

    // ws layout (zeroed region first)
    char* p = (char*)d_ws;
    ushort* nb_sum = (ushort*)p;              p += (size_t)N * D * 2;  // 6.4 MB
    float*  deg    = (float*)p;               p += (size_t)N * 4;      // 200 KB
    size_t zbytes  = (size_t)(p - (char*)d_ws);
    ushort* nb_b   = (ushort*)p;              p += (size_t)N * D * 2;  // 6.4 MB
    ushort* nf_b   = (ushort*)p;              p += (size_t)N * D * 2;  // 6.4 MB
    ushort* Wt_e   = (ushort*)p;              p += 64 * 64 * 2;
    ushort* Wt_d   = (ushort*)p;              p += 64 * 128 * 2;
    float*  bias2  = (float*)p;

    hipMemsetAsync(d_ws, 0, zbytes, stream);
    setup_kernel<<<1, 256, 0, stream>>>(W_edge, W_dense, b_dense, bias_edge, Wt_e, Wt_d, bias2);
    node_proj_kernel<<<(N + 15) / 16, 256, 0, stream>>>(nf, W_node, bias_node, nf_out, nf_b, N);
    edge_proj_accum_kernel<<<(E + 63) / 64, 256, 0, stream>>>(ef, dst, Wt_e, nb_sum, deg, E);
    finalize_nb_kernel<<<(int)(((size_t)N * D / 8 + 255) / 256), 256, 0, stream>>>(
        nb_sum, deg, nb_b, (long)N * D / 8);
    edge_out_kernel<<<(E + 63) / 64, 256, 0, stream>>>(ef, src, dst, Wt_e, Wt_d, nb_b, nf_b,
                                                       bias2, ef_out, E);
}

// Round 4
// 445.743 us; speedup vs baseline: 1.0704x; 1.0704x over previous
//
#include <hip/hip_runtime.h>

#define D 64

typedef __attribute__((ext_vector_type(8))) short short8;
typedef __attribute__((ext_vector_type(4))) float f32x4;

__device__ __forceinline__ ushort f2b(float f) {
    union { float f; unsigned u; } x; x.f = f;
    unsigned r = x.u + 0x7FFFu + ((x.u >> 16) & 1u);   // RNE to bf16
    return (ushort)(r >> 16);
}
__device__ __forceinline__ float b2f(ushort u) {
    union { float f; unsigned u; } x; x.u = ((unsigned)u) << 16;
    return x.f;
}
__device__ __forceinline__ short8 pack8(float4 a, float4 b) {
    short8 r;
    r[0] = (short)f2b(a.x); r[1] = (short)f2b(a.y); r[2] = (short)f2b(a.z); r[3] = (short)f2b(a.w);
    r[4] = (short)f2b(b.x); r[5] = (short)f2b(b.y); r[6] = (short)f2b(b.z); r[7] = (short)f2b(b.w);
    return r;
}

// ---------------------------------------------------------------------------
// Setup: Wcomb = W_edge @ W_dense[0:64]  (f32 table for VALU + bf16 B-frag
// table for MFMA), fused bias2 = b_dense + bias_edge.
// ---------------------------------------------------------------------------
__global__ __launch_bounds__(256) void setup_kernel(
    const float* __restrict__ W_edge, const float* __restrict__ W_dense,
    const float* __restrict__ b_dense, const float* __restrict__ bias_edge,
    float* __restrict__ Wcomb_f, ushort* __restrict__ Wcomb_b,
    float* __restrict__ bias2)
{
    const int tid = threadIdx.x;
    for (int idx = tid; idx < D * D; idx += 256) {
        int k = idx >> 6, n = idx & 63;
        float s = 0.f;
        #pragma unroll 8
        for (int j = 0; j < D; ++j)
            s = fmaf(W_edge[k * D + j], W_dense[j * D + n], s);
        Wcomb_f[k * D + n] = s;
        Wcomb_b[n * D + k] = f2b(s);   // B-fragment layout [n][k]
    }
    if (tid < D) bias2[tid] = b_dense[tid] + bias_edge[tid];
}

// ---------------------------------------------------------------------------
// Kernel 1: nf_out = relu(nf @ W_node + bias_node)  (f32 out + bf16 shadow)
// ---------------------------------------------------------------------------
__global__ __launch_bounds__(256) void node_proj_kernel(
    const float* __restrict__ nf, const float* __restrict__ W,
    const float* __restrict__ bias, float* __restrict__ out,
    ushort* __restrict__ out_b, int N)
{
    constexpr int ROWS = 16;
    __shared__ float Ws[D * D];
    __shared__ float As[ROWS * D];
    const int tid = threadIdx.x;
    const long row0 = (long)blockIdx.x * ROWS;

    #pragma unroll
    for (int i = tid; i < D * D / 4; i += 256)
        ((float4*)Ws)[i] = ((const float4*)W)[i];
    {
        int i = tid;  // ROWS*D/4 == 256
        long r = row0 + (i * 4) / D;
        ((float4*)As)[i] = (r < N) ? ((const float4*)nf)[row0 * D / 4 + i]
                                   : make_float4(0.f, 0.f, 0.f, 0.f);
    }
    __syncthreads();

    const int c = tid & 63;
    const float b = bias[c];
    for (int rr = tid >> 6; rr < ROWS; rr += 4) {
        float acc = 0.f;
        #pragma unroll
        for (int k = 0; k < D; ++k)
            acc = fmaf(As[rr * D + k], Ws[k * D + c], acc);
        long r = row0 + rr;
        if (r < N) {
            float v = fmaxf(acc + b, 0.f);
            out[r * D + c] = v;
            out_b[r * D + c] = f2b(v);
        }
    }
}

// ---------------------------------------------------------------------------
// Kernel 2: nfp = nf_relu @ (0.5 * W_dense[64:128])   -> bf16 table
// ---------------------------------------------------------------------------
__global__ __launch_bounds__(256) void nfp_kernel(
    const ushort* __restrict__ nfr_b, const float* __restrict__ W_dense,
    ushort* __restrict__ nfp_b, int N)
{
    constexpr int ROWS = 16;
    __shared__ float Wb[D * D];
    __shared__ float Xs[ROWS * D];
    const int tid = threadIdx.x;
    const long row0 = (long)blockIdx.x * ROWS;

    #pragma unroll
    for (int i = tid; i < D * D / 4; i += 256) {
        float4 v = ((const float4*)(W_dense + D * D))[i];  // bottom half rows
        ((float4*)Wb)[i] = make_float4(0.5f * v.x, 0.5f * v.y, 0.5f * v.z, 0.5f * v.w);
    }
    #pragma unroll
    for (int i = tid; i < ROWS * D; i += 256) {
        long r = row0 + (i >> 6);
        Xs[i] = (r < N) ? b2f(nfr_b[r * D + (i & 63)]) : 0.f;
    }
    __syncthreads();

    const int c = tid & 63;
    for (int rr = tid >> 6; rr < ROWS; rr += 4) {
        float acc = 0.f;
        #pragma unroll
        for (int k = 0; k < D; ++k)
            acc = fmaf(Xs[rr * D + k], Wb[k * D + c], acc);
        long r = row0 + rr;
        if (r < N) nfp_b[r * D + c] = f2b(acc);
    }
}

// ---------------------------------------------------------------------------
// Counting sort of edges by dst: hist -> scan (3 stages) -> scatter ids
// ---------------------------------------------------------------------------
__global__ __launch_bounds__(256) void hist_kernel(
    const int* __restrict__ dst, int* __restrict__ deg_i, int E)
{
    int i = blockIdx.x * 256 + threadIdx.x;
    if (i < E) atomicAdd(deg_i + dst[i], 1);
}

__global__ __launch_bounds__(256) void scanA_kernel(
    const int* __restrict__ deg_i, int* __restrict__ pos,
    int* __restrict__ bsum, int N)
{
    __shared__ int s[256];
    const int tid = threadIdx.x;
    const int i = blockIdx.x * 256 + tid;
    int v = (i < N) ? deg_i[i] : 0;
    s[tid] = v;
    __syncthreads();
    #pragma unroll
    for (int off = 1; off < 256; off <<= 1) {
        int t = (tid >= off) ? s[tid - off] : 0;
        __syncthreads();
        s[tid] += t;
        __syncthreads();
    }
    if (i < N) pos[i] = s[tid] - v;          // block-local exclusive
    if (tid == 255) bsum[blockIdx.x] = s[255];
}

__global__ __launch_bounds__(256) void scanB_kernel(int* __restrict__ bsum, int NB)
{
    __shared__ int s[256];
    const int tid = threadIdx.x;
    int v = (tid < NB) ? bsum[tid] : 0;
    s[tid] = v;
    __syncthreads();
    #pragma unroll
    for (int off = 1; off < 256; off <<= 1) {
        int t = (tid >= off) ? s[tid - off] : 0;
        __syncthreads();
        s[tid] += t;
        __syncthreads();
    }
    if (tid < NB) bsum[tid] = s[tid] - v;    // exclusive
}

__global__ __launch_bounds__(256) void scanC_kernel(
    int* __restrict__ pos, int* __restrict__ cursor,
    const int* __restrict__ bsum, int N)
{
    int i = blockIdx.x * 256 + threadIdx.x;
    if (i < N) {
        int p = pos[i] + bsum[blockIdx.x];
        pos[i] = p;
        cursor[i] = p;
    }
}

__global__ __launch_bounds__(256) void scatter_kernel(
    const int* __restrict__ dst, int* __restrict__ cursor,
    int* __restrict__ edge_ids, int E)
{
    int i = blockIdx.x * 256 + threadIdx.x;
    if (i < E) {
        int slot = atomicAdd(cursor + dst[i], 1);
        edge_ids[slot] = i;
    }
}

// ---------------------------------------------------------------------------
// Kernel D: segmean_b[n] = bf16( (sum of raw ef rows with dst==n) / max(deg,1) )
// One wave per node; lane = column.
// ---------------------------------------------------------------------------
__global__ __launch_bounds__(256) void segmean_kernel(
    const float* __restrict__ ef, const int* __restrict__ edge_ids,
    const int* __restrict__ pos, const int* __restrict__ deg_i,
    ushort* __restrict__ seg_b, int N)
{
    const int w = threadIdx.x >> 6, lane = threadIdx.x & 63;
    const int n = blockIdx.x * 4 + w;
    if (n >= N) return;
    const int p0 = pos[n], d = deg_i[n];
    float acc = 0.f;
    for (int base = 0; base < d; base += 64) {
        int m = min(64, d - base);
        int idv = (base + lane < d) ? edge_ids[p0 + base + lane] : 0;
        for (int j = 0; j < m; ++j) {
            int e = __shfl(idv, j, 64);
            acc += ef[(long)e * D + lane];
        }
    }
    float inv = 1.0f / fmaxf((float)d, 1.0f);
    seg_b[(long)n * D + lane] = f2b(acc * inv);
}

// ---------------------------------------------------------------------------
// Kernel E: ndp = segmean @ Wcomb + nfp    -> bf16 table (per-node dst-side add)
// ---------------------------------------------------------------------------
__global__ __launch_bounds__(256) void ndp_kernel(
    const ushort* __restrict__ seg_b, const float* __restrict__ Wcomb_f,
    const ushort* __restrict__ nfp_b, ushort* __restrict__ ndp_b, int N)
{
    constexpr int ROWS = 16;
    __shared__ float Wc[D * D];
    __shared__ float Xs[ROWS * D];
    const int tid = threadIdx.x;
    const long row0 = (long)blockIdx.x * ROWS;

    #pragma unroll
    for (int i = tid; i < D * D / 4; i += 256)
        ((float4*)Wc)[i] = ((const float4*)Wcomb_f)[i];
    #pragma unroll
    for (int i = tid; i < ROWS * D; i += 256) {
        long r = row0 + (i >> 6);
        Xs[i] = (r < N) ? b2f(seg_b[r * D + (i & 63)]) : 0.f;
    }
    __syncthreads();

    const int c = tid & 63;
    for (int rr = tid >> 6; rr < ROWS; rr += 4) {
        float acc = 0.f;
        #pragma unroll
        for (int k = 0; k < D; ++k)
            acc = fmaf(Xs[rr * D + k], Wc[k * D + c], acc);
        long r = row0 + rr;
        if (r < N) ndp_b[r * D + c] = f2b(acc + b2f(nfp_b[r * D + c]));
    }
}

// ---------------------------------------------------------------------------
// Kernel F: ef_out = relu( ef @ Wcomb + ndp[dst] + nfp[src] + bias2 )
// 64 edges/block, 4 waves, single K=64 MFMA GEMM; gathers staged to LDS (f32)
// and added in the epilogue.
// ---------------------------------------------------------------------------
__global__ __launch_bounds__(256) void edge_out_kernel(
    const float* __restrict__ ef, const int* __restrict__ src,
    const int* __restrict__ dst, const ushort* __restrict__ Wcomb_b,
    const ushort* __restrict__ ndp_b, const ushort* __restrict__ nfp_b,
    const float* __restrict__ bias2, float* __restrict__ out, int E)
{
    __shared__ float Bias[64 * 68];    // 17408 B, stride 68 floats
    const int tid = threadIdx.x;
    const long row0 = (long)blockIdx.x * 64;

    {   // gather stage: 4 threads/edge, 16 cols each
        int e = tid >> 2, q = tid & 3;
        long er = row0 + e; if (er >= E) er = E - 1;
        int dv = dst[er], sv = src[er];
        const short8* np = (const short8*)(ndp_b + (long)dv * D + q * 16);
        const short8* sp = (const short8*)(nfp_b + (long)sv * D + q * 16);
        short8 n0 = np[0], n1 = np[1];
        short8 s0 = sp[0], s1 = sp[1];
        float* bp = &Bias[e * 68 + q * 16];
        #pragma unroll
        for (int j = 0; j < 8; ++j) {
            bp[j]     = b2f((ushort)n0[j]) + b2f((ushort)s0[j]);
            bp[8 + j] = b2f((ushort)n1[j]) + b2f((ushort)s1[j]);
        }
    }

    const int w = tid >> 6, lane = tid & 63;
    const int lr = lane & 15, g = lane >> 4;
    const int arow = 16 * w + lr;
    long era = row0 + arow; if (era >= E) era = E - 1;

    // A fragments from global ef (row=lr, k=8g..8g+7 / 32+8g..)
    const float4* ap = (const float4*)(ef + era * D);
    float4 v0 = ap[2 * g], v1 = ap[2 * g + 1];
    float4 v2 = ap[8 + 2 * g], v3 = ap[8 + 2 * g + 1];
    short8 a0 = pack8(v0, v1), a1 = pack8(v2, v3);

    f32x4 acc[4];
    #pragma unroll
    for (int t = 0; t < 4; ++t) {
        f32x4 z = {0.f, 0.f, 0.f, 0.f};
        short8 b0 = *(const short8*)&Wcomb_b[(16 * t + lr) * D + 8 * g];
        short8 b1 = *(const short8*)&Wcomb_b[(16 * t + lr) * D + 32 + 8 * g];
        z = __builtin_amdgcn_mfma_f32_16x16x32_bf16(a0, b0, z, 0, 0, 0);
        z = __builtin_amdgcn_mfma_f32_16x16x32_bf16(a1, b1, z, 0, 0, 0);
        acc[t] = z;
    }
    __syncthreads();

    // epilogue: + Bias LDS + bias2, relu, store
    #pragma unroll
    for (int t = 0; t < 4; ++t) {
        int c = 16 * t + lr;
        float bsum = bias2[c];
        #pragma unroll
        for (int reg = 0; reg < 4; ++reg) {
            int rl = 16 * w + 4 * g + reg;
            long r = row0 + rl;
            if (r < E) out[r * D + c] = fmaxf(acc[t][reg] + Bias[rl * 68 + c] + bsum, 0.f);
        }
    }
}

// ---------------------------------------------------------------------------
extern "C" void kernel_launch(void* const* d_in, const int* in_sizes, int n_in,
                              void* d_out, int out_size, void* d_ws, size_t ws_size,
                              hipStream_t stream) {
    const float* nf        = (const float*)d_in[0];
    const float* ef        = (const float*)d_in[1];
    const int*   src       = (const int*)d_in[2];
    const int*   dst       = (const int*)d_in[3];
    const float* W_node    = (const float*)d_in[4];
    const float* W_edge    = (const float*)d_in[5];
    const float* bias_node = (const float*)d_in[6];
    const float* bias_edge = (const float*)d_in[7];
    const float* W_dense   = (const float*)d_in[8];
    const float* b_dense   = (const float*)d_in[9];

    const int N = in_sizes[0] / D;
    const int E = in_sizes[1] / D;
    const int NB = (N + 255) / 256;

    float* nf_out = (float*)d_out;
    float* ef_out = (float*)d_out + (size_t)N * D;

    // ws layout
    char* p = (char*)d_ws;
    int*    deg_i   = (int*)p;      p += (size_t)N * 4;          // zeroed
    int*    pos     = (int*)p;      p += (size_t)N * 4;
    int*    cursor  = (int*)p;      p += (size_t)N * 4;
    int*    bsum    = (int*)p;      p += 256 * 4;
    int*    edge_ids= (int*)p;      p += (size_t)E * 4;
    ushort* nfr_b   = (ushort*)p;   p += (size_t)N * D * 2;
    ushort* nfp_b   = (ushort*)p;   p += (size_t)N * D * 2;
    ushort* seg_b   = (ushort*)p;   p += (size_t)N * D * 2;
    ushort* ndp_b   = (ushort*)p;   p += (size_t)N * D * 2;
    float*  Wcomb_f = (float*)p;    p += D * D * 4;
    ushort* Wcomb_b = (ushort*)p;   p += D * D * 2;
    float*  bias2   = (float*)p;

    hipMemsetAsync(deg_i, 0, (size_t)N * 4, stream);

    setup_kernel<<<1, 256, 0, stream>>>(W_edge, W_dense, b_dense, bias_edge,
                                        Wcomb_f, Wcomb_b, bias2);
    node_proj_kernel<<<(N + 15) / 16, 256, 0, stream>>>(nf, W_node, bias_node,
                                                        nf_out, nfr_b, N);
    nfp_kernel<<<(N + 15) / 16, 256, 0, stream>>>(nfr_b, W_dense, nfp_b, N);
    hist_kernel<<<(E + 255) / 256, 256, 0, stream>>>(dst, deg_i, E);
    scanA_kernel<<<NB, 256, 0, stream>>>(deg_i, pos, bsum, N);
    scanB_kernel<<<1, 256, 0, stream>>>(bsum, NB);
    scanC_kernel<<<NB, 256, 0, stream>>>(pos, cursor, bsum, N);
    scatter_kernel<<<(E + 255) / 256, 256, 0, stream>>>(dst, cursor, edge_ids, E);
    segmean_kernel<<<(N + 3) / 4, 256, 0, stream>>>(ef, edge_ids, pos, deg_i, seg_b, N);
    ndp_kernel<<<(N + 15) / 16, 256, 0, stream>>>(seg_b, Wcomb_f, nfp_b, ndp_b, N);
    edge_out_kernel<<<(E + 63) / 64, 256, 0, stream>>>(ef, src, dst, Wcomb_b,
                                                       ndp_b, nfp_b, bias2, ef_out, E);
}

// Round 5
// 403.911 us; speedup vs baseline: 1.1812x; 1.1036x over previous
//
#include <hip/hip_runtime.h>

#define D 64

typedef __attribute__((ext_vector_type(8))) short short8;
typedef __attribute__((ext_vector_type(4))) float f32x4;

__device__ __forceinline__ ushort f2b(float f) {
    union { float f; unsigned u; } x; x.f = f;
    unsigned r = x.u + 0x7FFFu + ((x.u >> 16) & 1u);   // RNE to bf16
    return (ushort)(r >> 16);
}
__device__ __forceinline__ float b2f(ushort u) {
    union { float f; unsigned u; } x; x.u = ((unsigned)u) << 16;
    return x.f;
}
__device__ __forceinline__ short8 pack8(float4 a, float4 b) {
    short8 r;
    r[0] = (short)f2b(a.x); r[1] = (short)f2b(a.y); r[2] = (short)f2b(a.z); r[3] = (short)f2b(a.w);
    r[4] = (short)f2b(b.x); r[5] = (short)f2b(b.y); r[6] = (short)f2b(b.z); r[7] = (short)f2b(b.w);
    return r;
}

// ---------------------------------------------------------------------------
// Setup: Wcomb = W_edge @ W_dense[0:64] (f32 table + bf16 B-frag table),
// bias2 = b_dense + bias_edge.
// ---------------------------------------------------------------------------
__global__ __launch_bounds__(256) void setup_kernel(
    const float* __restrict__ W_edge, const float* __restrict__ W_dense,
    const float* __restrict__ b_dense, const float* __restrict__ bias_edge,
    float* __restrict__ Wcomb_f, ushort* __restrict__ Wcomb_b,
    float* __restrict__ bias2)
{
    const int tid = threadIdx.x;
    for (int idx = tid; idx < D * D; idx += 256) {
        int k = idx >> 6, n = idx & 63;
        float s = 0.f;
        #pragma unroll 8
        for (int j = 0; j < D; ++j)
            s = fmaf(W_edge[k * D + j], W_dense[j * D + n], s);
        Wcomb_f[k * D + n] = s;
        Wcomb_b[n * D + k] = f2b(s);   // B-fragment layout [n][k]
    }
    if (tid < D) bias2[tid] = b_dense[tid] + bias_edge[tid];
}

// ---------------------------------------------------------------------------
// Kernel 1 (fused): nf_out = relu(nf @ W_node + bias_node)  (f32, exact)
//                   nfp_b  = bf16( nf_out @ (0.5 * W_dense[64:128]) )
// ---------------------------------------------------------------------------
__global__ __launch_bounds__(256) void node_proj_kernel(
    const float* __restrict__ nf, const float* __restrict__ Wn,
    const float* __restrict__ bias, const float* __restrict__ Wd_bot,
    float* __restrict__ out, ushort* __restrict__ nfp_b, int N)
{
    constexpr int ROWS = 16;
    __shared__ float Ws[D * D];
    __shared__ float Wb[D * D];
    __shared__ float As[ROWS * D];
    __shared__ float Vs[ROWS * D];
    const int tid = threadIdx.x;
    const long row0 = (long)blockIdx.x * ROWS;

    #pragma unroll
    for (int i = tid; i < D * D / 4; i += 256) {
        ((float4*)Ws)[i] = ((const float4*)Wn)[i];
        float4 v = ((const float4*)Wd_bot)[i];
        ((float4*)Wb)[i] = make_float4(0.5f * v.x, 0.5f * v.y, 0.5f * v.z, 0.5f * v.w);
    }
    {
        int i = tid;  // ROWS*D/4 == 256
        long r = row0 + (i * 4) / D;
        ((float4*)As)[i] = (r < N) ? ((const float4*)nf)[row0 * D / 4 + i]
                                   : make_float4(0.f, 0.f, 0.f, 0.f);
    }
    __syncthreads();

    const int c = tid & 63;
    const float b = bias[c];
    for (int rr = tid >> 6; rr < ROWS; rr += 4) {
        float acc = 0.f;
        #pragma unroll
        for (int k = 0; k < D; ++k)
            acc = fmaf(As[rr * D + k], Ws[k * D + c], acc);
        float v = fmaxf(acc + b, 0.f);
        Vs[rr * D + c] = v;
        long r = row0 + rr;
        if (r < N) out[r * D + c] = v;
    }
    __syncthreads();
    for (int rr = tid >> 6; rr < ROWS; rr += 4) {
        float acc = 0.f;
        #pragma unroll
        for (int k = 0; k < D; ++k)
            acc = fmaf(Vs[rr * D + k], Wb[k * D + c], acc);
        long r = row0 + rr;
        if (r < N) nfp_b[r * D + c] = f2b(acc);
    }
}

// ---------------------------------------------------------------------------
// Counting sort of edges by dst: hist -> scan (3 stages) -> scatter ids
// ---------------------------------------------------------------------------
__global__ __launch_bounds__(256) void hist_kernel(
    const int* __restrict__ dst, int* __restrict__ deg_i, int E)
{
    int i = blockIdx.x * 256 + threadIdx.x;
    if (i < E) atomicAdd(deg_i + dst[i], 1);
}

__global__ __launch_bounds__(256) void scanA_kernel(
    const int* __restrict__ deg_i, int* __restrict__ pos,
    int* __restrict__ bsum, int N)
{
    __shared__ int s[256];
    const int tid = threadIdx.x;
    const int i = blockIdx.x * 256 + tid;
    int v = (i < N) ? deg_i[i] : 0;
    s[tid] = v;
    __syncthreads();
    #pragma unroll
    for (int off = 1; off < 256; off <<= 1) {
        int t = (tid >= off) ? s[tid - off] : 0;
        __syncthreads();
        s[tid] += t;
        __syncthreads();
    }
    if (i < N) pos[i] = s[tid] - v;          // block-local exclusive
    if (tid == 255) bsum[blockIdx.x] = s[255];
}

__global__ __launch_bounds__(256) void scanB_kernel(int* __restrict__ bsum, int NB)
{
    __shared__ int s[256];
    const int tid = threadIdx.x;
    int v = (tid < NB) ? bsum[tid] : 0;
    s[tid] = v;
    __syncthreads();
    #pragma unroll
    for (int off = 1; off < 256; off <<= 1) {
        int t = (tid >= off) ? s[tid - off] : 0;
        __syncthreads();
        s[tid] += t;
        __syncthreads();
    }
    if (tid < NB) bsum[tid] = s[tid] - v;    // exclusive
}

__global__ __launch_bounds__(256) void scanC_kernel(
    int* __restrict__ pos, int* __restrict__ cursor,
    const int* __restrict__ bsum, int N)
{
    int i = blockIdx.x * 256 + threadIdx.x;
    if (i < N) {
        int p = pos[i] + bsum[blockIdx.x];
        pos[i] = p;
        cursor[i] = p;
    }
}

__global__ __launch_bounds__(256) void scatter_kernel(
    const int* __restrict__ dst, int* __restrict__ cursor,
    int* __restrict__ edge_ids, int E)
{
    int i = blockIdx.x * 256 + threadIdx.x;
    if (i < E) {
        int slot = atomicAdd(cursor + dst[i], 1);
        edge_ids[slot] = i;
    }
}

// ===========================================================================
// PATH A (big workspace): materialize efp = bf16(ef @ Wcomb) once.
// ===========================================================================

// efp_kernel: 64 edges/block, 4 waves, K=64 MFMA; packed dword stores.
__global__ __launch_bounds__(256) void efp_kernel(
    const float* __restrict__ ef, const ushort* __restrict__ Wt,
    ushort* __restrict__ efp, int E)
{
    const int tid = threadIdx.x;
    const long row0 = (long)blockIdx.x * 64;
    const int w = tid >> 6, lane = tid & 63;
    const int lr = lane & 15, g = lane >> 4;
    const int arow = 16 * w + lr;
    long era = row0 + arow; if (era >= E) era = E - 1;

    const float4* ap = (const float4*)(ef + era * D);
    float4 v0 = ap[2 * g], v1 = ap[2 * g + 1];
    float4 v2 = ap[8 + 2 * g], v3 = ap[8 + 2 * g + 1];
    short8 a0 = pack8(v0, v1), a1 = pack8(v2, v3);

    f32x4 acc[4];
    #pragma unroll
    for (int t = 0; t < 4; ++t) {
        f32x4 z = {0.f, 0.f, 0.f, 0.f};
        short8 b0 = *(const short8*)&Wt[(16 * t + lr) * D + 8 * g];
        short8 b1 = *(const short8*)&Wt[(16 * t + lr) * D + 32 + 8 * g];
        z = __builtin_amdgcn_mfma_f32_16x16x32_bf16(a0, b0, z, 0, 0, 0);
        z = __builtin_amdgcn_mfma_f32_16x16x32_bf16(a1, b1, z, 0, 0, 0);
        acc[t] = z;
    }

    // Packed store: lane pair (lr, lr^1) covers cols (c0, c0+1).
    const bool odd = lane & 1;
    const int rb = 16 * w + 4 * g + (odd ? 2 : 0);
    long e0 = row0 + rb, e1 = row0 + rb + 1;
    #pragma unroll
    for (int t = 0; t < 4; ++t) {
        float p0 = __shfl_xor(acc[t][0], 1, 64);
        float p1 = __shfl_xor(acc[t][1], 1, 64);
        float p2 = __shfl_xor(acc[t][2], 1, 64);
        float p3 = __shfl_xor(acc[t][3], 1, 64);
        float lo0, hi0, lo1, hi1;
        if (odd) { lo0 = p2; hi0 = acc[t][2]; lo1 = p3; hi1 = acc[t][3]; }
        else     { lo0 = acc[t][0]; hi0 = p0; lo1 = acc[t][1]; hi1 = p1; }
        int cbase = 16 * t + (lr & ~1);
        unsigned dw0 = ((unsigned)f2b(hi0) << 16) | (unsigned)f2b(lo0);
        unsigned dw1 = ((unsigned)f2b(hi1) << 16) | (unsigned)f2b(lo1);
        if (e0 < E) *(unsigned*)(efp + e0 * D + cbase) = dw0;
        if (e1 < E) *(unsigned*)(efp + e1 * D + cbase) = dw1;
    }
}

// segmean_ndp: one wave per node; 8 edges x 8 col-blocks per iteration.
// ndp[n] = mean(efp rows with dst==n) + nfp[n].
__global__ __launch_bounds__(256) void segmean_ndp_kernel(
    const ushort* __restrict__ efp, const int* __restrict__ edge_ids,
    const int* __restrict__ pos, const int* __restrict__ deg_i,
    const ushort* __restrict__ nfp_b, ushort* __restrict__ ndp_b, int N)
{
    const int w = threadIdx.x >> 6, lane = threadIdx.x & 63;
    const int n = blockIdx.x * 4 + w;
    if (n >= N) return;
    const int p0 = pos[n], d = deg_i[n];
    const int cb = lane & 7;      // col block: cols 8*cb .. 8*cb+7
    const int es = lane >> 3;     // edge slot 0..7

    float acc0 = 0.f, acc1 = 0.f, acc2 = 0.f, acc3 = 0.f;
    float acc4 = 0.f, acc5 = 0.f, acc6 = 0.f, acc7 = 0.f;
    for (int base = 0; base < d; base += 8) {
        int j = base + es;
        if (j < d) {
            int eid = edge_ids[p0 + j];
            short8 v = *(const short8*)(efp + (long)eid * D + cb * 8);
            acc0 += b2f((ushort)v[0]); acc1 += b2f((ushort)v[1]);
            acc2 += b2f((ushort)v[2]); acc3 += b2f((ushort)v[3]);
            acc4 += b2f((ushort)v[4]); acc5 += b2f((ushort)v[5]);
            acc6 += b2f((ushort)v[6]); acc7 += b2f((ushort)v[7]);
        }
    }
    #pragma unroll
    for (int m = 8; m < 64; m <<= 1) {
        acc0 += __shfl_xor(acc0, m, 64); acc1 += __shfl_xor(acc1, m, 64);
        acc2 += __shfl_xor(acc2, m, 64); acc3 += __shfl_xor(acc3, m, 64);
        acc4 += __shfl_xor(acc4, m, 64); acc5 += __shfl_xor(acc5, m, 64);
        acc6 += __shfl_xor(acc6, m, 64); acc7 += __shfl_xor(acc7, m, 64);
    }
    if (es == 0) {
        float inv = 1.0f / fmaxf((float)d, 1.0f);
        short8 np = *(const short8*)(nfp_b + (long)n * D + cb * 8);
        short8 r;
        r[0] = (short)f2b(acc0 * inv + b2f((ushort)np[0]));
        r[1] = (short)f2b(acc1 * inv + b2f((ushort)np[1]));
        r[2] = (short)f2b(acc2 * inv + b2f((ushort)np[2]));
        r[3] = (short)f2b(acc3 * inv + b2f((ushort)np[3]));
        r[4] = (short)f2b(acc4 * inv + b2f((ushort)np[4]));
        r[5] = (short)f2b(acc5 * inv + b2f((ushort)np[5]));
        r[6] = (short)f2b(acc6 * inv + b2f((ushort)np[6]));
        r[7] = (short)f2b(acc7 * inv + b2f((ushort)np[7]));
        *(short8*)(ndp_b + (long)n * D + cb * 8) = r;
    }
}

// final: ef_out = relu(efp + ndp[dst] + nfp[src] + bias2). Pure elementwise.
// 4 threads per edge, 16 cols each.
__global__ __launch_bounds__(256) void final_kernel(
    const ushort* __restrict__ efp, const int* __restrict__ src,
    const int* __restrict__ dst, const ushort* __restrict__ ndp_b,
    const ushort* __restrict__ nfp_b, const float* __restrict__ bias2,
    float* __restrict__ out, int E)
{
    long idx = (long)blockIdx.x * 256 + threadIdx.x;
    long e = idx >> 2;
    int q = (int)(idx & 3);
    if (e >= E) return;
    int dv = dst[e], sv = src[e];
    const short8* ep = (const short8*)(efp + e * D + q * 16);
    const short8* np = (const short8*)(ndp_b + (long)dv * D + q * 16);
    const short8* sp = (const short8*)(nfp_b + (long)sv * D + q * 16);
    short8 e0 = ep[0], e1 = ep[1];
    short8 n0 = np[0], n1 = np[1];
    short8 s0 = sp[0], s1 = sp[1];
    const float4* bp = (const float4*)(bias2 + q * 16);
    float4 b0 = bp[0], b1 = bp[1], b2 = bp[2], b3 = bp[3];

    float r[16];
    #pragma unroll
    for (int j = 0; j < 8; ++j) {
        r[j]     = b2f((ushort)e0[j]) + b2f((ushort)n0[j]) + b2f((ushort)s0[j]);
        r[8 + j] = b2f((ushort)e1[j]) + b2f((ushort)n1[j]) + b2f((ushort)s1[j]);
    }
    float4* op = (float4*)(out + e * D + q * 16);
    op[0] = make_float4(fmaxf(r[0] + b0.x, 0.f), fmaxf(r[1] + b0.y, 0.f),
                        fmaxf(r[2] + b0.z, 0.f), fmaxf(r[3] + b0.w, 0.f));
    op[1] = make_float4(fmaxf(r[4] + b1.x, 0.f), fmaxf(r[5] + b1.y, 0.f),
                        fmaxf(r[6] + b1.z, 0.f), fmaxf(r[7] + b1.w, 0.f));
    op[2] = make_float4(fmaxf(r[8] + b2.x, 0.f), fmaxf(r[9] + b2.y, 0.f),
                        fmaxf(r[10] + b2.z, 0.f), fmaxf(r[11] + b2.w, 0.f));
    op[3] = make_float4(fmaxf(r[12] + b3.x, 0.f), fmaxf(r[13] + b3.y, 0.f),
                        fmaxf(r[14] + b3.z, 0.f), fmaxf(r[15] + b3.w, 0.f));
}

// ===========================================================================
// PATH B (fallback, small workspace): round-4 proven kernels.
// ===========================================================================
__global__ __launch_bounds__(256) void segmean_kernel(
    const float* __restrict__ ef, const int* __restrict__ edge_ids,
    const int* __restrict__ pos, const int* __restrict__ deg_i,
    ushort* __restrict__ seg_b, int N)
{
    const int w = threadIdx.x >> 6, lane = threadIdx.x & 63;
    const int n = blockIdx.x * 4 + w;
    if (n >= N) return;
    const int p0 = pos[n], d = deg_i[n];
    float acc = 0.f;
    for (int base = 0; base < d; base += 64) {
        int m = min(64, d - base);
        int idv = (base + lane < d) ? edge_ids[p0 + base + lane] : 0;
        for (int j = 0; j < m; ++j) {
            int e = __shfl(idv, j, 64);
            acc += ef[(long)e * D + lane];
        }
    }
    float inv = 1.0f / fmaxf((float)d, 1.0f);
    seg_b[(long)n * D + lane] = f2b(acc * inv);
}

__global__ __launch_bounds__(256) void ndp_kernel(
    const ushort* __restrict__ seg_b, const float* __restrict__ Wcomb_f,
    const ushort* __restrict__ nfp_b, ushort* __restrict__ ndp_b, int N)
{
    constexpr int ROWS = 16;
    __shared__ float Wc[D * D];
    __shared__ float Xs[ROWS * D];
    const int tid = threadIdx.x;
    const long row0 = (long)blockIdx.x * ROWS;

    #pragma unroll
    for (int i = tid; i < D * D / 4; i += 256)
        ((float4*)Wc)[i] = ((const float4*)Wcomb_f)[i];
    #pragma unroll
    for (int i = tid; i < ROWS * D; i += 256) {
        long r = row0 + (i >> 6);
        Xs[i] = (r < N) ? b2f(seg_b[r * D + (i & 63)]) : 0.f;
    }
    __syncthreads();

    const int c = tid & 63;
    for (int rr = tid >> 6; rr < ROWS; rr += 4) {
        float acc = 0.f;
        #pragma unroll
        for (int k = 0; k < D; ++k)
            acc = fmaf(Xs[rr * D + k], Wc[k * D + c], acc);
        long r = row0 + rr;
        if (r < N) ndp_b[r * D + c] = f2b(acc + b2f(nfp_b[r * D + c]));
    }
}

__global__ __launch_bounds__(256) void edge_out_kernel(
    const float* __restrict__ ef, const int* __restrict__ src,
    const int* __restrict__ dst, const ushort* __restrict__ Wcomb_b,
    const ushort* __restrict__ ndp_b, const ushort* __restrict__ nfp_b,
    const float* __restrict__ bias2, float* __restrict__ out, int E)
{
    __shared__ float Bias[64 * 68];
    const int tid = threadIdx.x;
    const long row0 = (long)blockIdx.x * 64;

    {
        int e = tid >> 2, q = tid & 3;
        long er = row0 + e; if (er >= E) er = E - 1;
        int dv = dst[er], sv = src[er];
        const short8* np = (const short8*)(ndp_b + (long)dv * D + q * 16);
        const short8* sp = (const short8*)(nfp_b + (long)sv * D + q * 16);
        short8 n0 = np[0], n1 = np[1];
        short8 s0 = sp[0], s1 = sp[1];
        float* bp = &Bias[e * 68 + q * 16];
        #pragma unroll
        for (int j = 0; j < 8; ++j) {
            bp[j]     = b2f((ushort)n0[j]) + b2f((ushort)s0[j]);
            bp[8 + j] = b2f((ushort)n1[j]) + b2f((ushort)s1[j]);
        }
    }

    const int w = tid >> 6, lane = tid & 63;
    const int lr = lane & 15, g = lane >> 4;
    const int arow = 16 * w + lr;
    long era = row0 + arow; if (era >= E) era = E - 1;

    const float4* ap = (const float4*)(ef + era * D);
    float4 v0 = ap[2 * g], v1 = ap[2 * g + 1];
    float4 v2 = ap[8 + 2 * g], v3 = ap[8 + 2 * g + 1];
    short8 a0 = pack8(v0, v1), a1 = pack8(v2, v3);

    f32x4 acc[4];
    #pragma unroll
    for (int t = 0; t < 4; ++t) {
        f32x4 z = {0.f, 0.f, 0.f, 0.f};
        short8 b0 = *(const short8*)&Wcomb_b[(16 * t + lr) * D + 8 * g];
        short8 b1 = *(const short8*)&Wcomb_b[(16 * t + lr) * D + 32 + 8 * g];
        z = __builtin_amdgcn_mfma_f32_16x16x32_bf16(a0, b0, z, 0, 0, 0);
        z = __builtin_amdgcn_mfma_f32_16x16x32_bf16(a1, b1, z, 0, 0, 0);
        acc[t] = z;
    }
    __syncthreads();

    #pragma unroll
    for (int t = 0; t < 4; ++t) {
        int c = 16 * t + lr;
        float bsum = bias2[c];
        #pragma unroll
        for (int reg = 0; reg < 4; ++reg) {
            int rl = 16 * w + 4 * g + reg;
            long r = row0 + rl;
            if (r < E) out[r * D + c] = fmaxf(acc[t][reg] + Bias[rl * 68 + c] + bsum, 0.f);
        }
    }
}

// ---------------------------------------------------------------------------
extern "C" void kernel_launch(void* const* d_in, const int* in_sizes, int n_in,
                              void* d_out, int out_size, void* d_ws, size_t ws_size,
                              hipStream_t stream) {
    const float* nf        = (const float*)d_in[0];
    const float* ef        = (const float*)d_in[1];
    const int*   src       = (const int*)d_in[2];
    const int*   dst       = (const int*)d_in[3];
    const float* W_node    = (const float*)d_in[4];
    const float* W_edge    = (const float*)d_in[5];
    const float* bias_node = (const float*)d_in[6];
    const float* bias_edge = (const float*)d_in[7];
    const float* W_dense   = (const float*)d_in[8];
    const float* b_dense   = (const float*)d_in[9];

    const int N = in_sizes[0] / D;
    const int E = in_sizes[1] / D;
    const int NB = (N + 255) / 256;

    float* nf_out = (float*)d_out;
    float* ef_out = (float*)d_out + (size_t)N * D;

    // ws layout
    char* p = (char*)d_ws;
    int*    deg_i   = (int*)p;      p += (size_t)N * 4;          // zeroed
    int*    pos     = (int*)p;      p += (size_t)N * 4;
    int*    cursor  = (int*)p;      p += (size_t)N * 4;
    int*    bsum    = (int*)p;      p += 256 * 4;
    int*    edge_ids= (int*)p;      p += (size_t)E * 4;
    ushort* nfp_b   = (ushort*)p;   p += (size_t)N * D * 2;
    ushort* ndp_b   = (ushort*)p;   p += (size_t)N * D * 2;
    ushort* seg_b   = (ushort*)p;   p += (size_t)N * D * 2;      // path B only
    float*  Wcomb_f = (float*)p;    p += D * D * 4;
    ushort* Wcomb_b = (ushort*)p;   p += D * D * 2;
    float*  bias2   = (float*)p;    p += 256;
    ushort* efp     = (ushort*)p;   p += (size_t)E * D * 2;      // path A only
    const size_t need = (size_t)(p - (char*)d_ws);
    const bool bigws = (ws_size >= need);

    hipMemsetAsync(deg_i, 0, (size_t)N * 4, stream);

    setup_kernel<<<1, 256, 0, stream>>>(W_edge, W_dense, b_dense, bias_edge,
                                        Wcomb_f, Wcomb_b, bias2);
    node_proj_kernel<<<(N + 15) / 16, 256, 0, stream>>>(nf, W_node, bias_node,
                                                        W_dense + D * D, nf_out, nfp_b, N);
    hist_kernel<<<(E + 255) / 256, 256, 0, stream>>>(dst, deg_i, E);
    scanA_kernel<<<NB, 256, 0, stream>>>(deg_i, pos, bsum, N);
    scanB_kernel<<<1, 256, 0, stream>>>(bsum, NB);
    scanC_kernel<<<NB, 256, 0, stream>>>(pos, cursor, bsum, N);
    scatter_kernel<<<(E + 255) / 256, 256, 0, stream>>>(dst, cursor, edge_ids, E);

    if (bigws) {
        efp_kernel<<<(E + 63) / 64, 256, 0, stream>>>(ef, Wcomb_b, efp, E);
        segmean_ndp_kernel<<<(N + 3) / 4, 256, 0, stream>>>(efp, edge_ids, pos, deg_i,
                                                            nfp_b, ndp_b, N);
        final_kernel<<<(int)(((size_t)E * 4 + 255) / 256), 256, 0, stream>>>(
            efp, src, dst, ndp_b, nfp_b, bias2, ef_out, E);
    } else {
        segmean_kernel<<<(N + 3) / 4, 256, 0, stream>>>(ef, edge_ids, pos, deg_i, seg_b, N);
        ndp_kernel<<<(N + 15) / 16, 256, 0, stream>>>(seg_b, Wcomb_f, nfp_b, ndp_b, N);
        edge_out_kernel<<<(E + 63) / 64, 256, 0, stream>>>(ef, src, dst, Wcomb_b,
                                                           ndp_b, nfp_b, bias2, ef_out, E);
    }
}

// Round 6
// 402.082 us; speedup vs baseline: 1.1866x; 1.0045x over previous
//
#include <hip/hip_runtime.h>

#define D 64

typedef __attribute__((ext_vector_type(8))) short short8;
typedef __attribute__((ext_vector_type(4))) float f32x4;

__device__ __forceinline__ ushort f2b(float f) {
    union { float f; unsigned u; } x; x.f = f;
    unsigned r = x.u + 0x7FFFu + ((x.u >> 16) & 1u);   // RNE to bf16
    return (ushort)(r >> 16);
}
__device__ __forceinline__ float b2f(ushort u) {
    union { float f; unsigned u; } x; x.u = ((unsigned)u) << 16;
    return x.f;
}
__device__ __forceinline__ short8 pack8(float4 a, float4 b) {
    short8 r;
    r[0] = (short)f2b(a.x); r[1] = (short)f2b(a.y); r[2] = (short)f2b(a.z); r[3] = (short)f2b(a.w);
    r[4] = (short)f2b(b.x); r[5] = (short)f2b(b.y); r[6] = (short)f2b(b.z); r[7] = (short)f2b(b.w);
    return r;
}

// ---------------------------------------------------------------------------
// Setup: Wcomb_b[n*64+k] = bf16( (W_edge @ W_dense[0:64])[k][n] ),
// bias2 = b_dense + bias_edge.
// ---------------------------------------------------------------------------
__global__ __launch_bounds__(256) void setup_kernel(
    const float* __restrict__ W_edge, const float* __restrict__ W_dense,
    const float* __restrict__ b_dense, const float* __restrict__ bias_edge,
    ushort* __restrict__ Wcomb_b, float* __restrict__ bias2)
{
    const int tid = threadIdx.x;
    for (int idx = tid; idx < D * D; idx += 256) {
        int k = idx >> 6, n = idx & 63;
        float s = 0.f;
        #pragma unroll 8
        for (int j = 0; j < D; ++j)
            s = fmaf(W_edge[k * D + j], W_dense[j * D + n], s);
        Wcomb_b[n * D + k] = f2b(s);   // B-fragment layout [n][k]
    }
    if (tid < D) bias2[tid] = b_dense[tid] + bias_edge[tid];
}

// ---------------------------------------------------------------------------
// Kernel 1 (fused): nf_out = relu(nf @ W_node + bias_node)  (f32, exact)
//                   nfp_b  = bf16( nf_out @ (0.5 * W_dense[64:128]) )
// ---------------------------------------------------------------------------
__global__ __launch_bounds__(256) void node_proj_kernel(
    const float* __restrict__ nf, const float* __restrict__ Wn,
    const float* __restrict__ bias, const float* __restrict__ Wd_bot,
    float* __restrict__ out, ushort* __restrict__ nfp_b, int N)
{
    constexpr int ROWS = 16;
    __shared__ float Ws[D * D];
    __shared__ float Wb[D * D];
    __shared__ float As[ROWS * D];
    __shared__ float Vs[ROWS * D];
    const int tid = threadIdx.x;
    const long row0 = (long)blockIdx.x * ROWS;

    #pragma unroll
    for (int i = tid; i < D * D / 4; i += 256) {
        ((float4*)Ws)[i] = ((const float4*)Wn)[i];
        float4 v = ((const float4*)Wd_bot)[i];
        ((float4*)Wb)[i] = make_float4(0.5f * v.x, 0.5f * v.y, 0.5f * v.z, 0.5f * v.w);
    }
    {
        int i = tid;  // ROWS*D/4 == 256
        long r = row0 + (i * 4) / D;
        ((float4*)As)[i] = (r < N) ? ((const float4*)nf)[row0 * D / 4 + i]
                                   : make_float4(0.f, 0.f, 0.f, 0.f);
    }
    __syncthreads();

    const int c = tid & 63;
    const float b = bias[c];
    for (int rr = tid >> 6; rr < ROWS; rr += 4) {
        float acc = 0.f;
        #pragma unroll
        for (int k = 0; k < D; ++k)
            acc = fmaf(As[rr * D + k], Ws[k * D + c], acc);
        float v = fmaxf(acc + b, 0.f);
        Vs[rr * D + c] = v;
        long r = row0 + rr;
        if (r < N) out[r * D + c] = v;
    }
    __syncthreads();
    for (int rr = tid >> 6; rr < ROWS; rr += 4) {
        float acc = 0.f;
        #pragma unroll
        for (int k = 0; k < D; ++k)
            acc = fmaf(Vs[rr * D + k], Wb[k * D + c], acc);
        long r = row0 + rr;
        if (r < N) nfp_b[r * D + c] = f2b(acc);
    }
}

// ---------------------------------------------------------------------------
// Counting sort of edges by dst: hist -> scan (3 stages) -> scatter (eid,dst)
// ---------------------------------------------------------------------------
__global__ __launch_bounds__(256) void hist_kernel(
    const int* __restrict__ dst, int* __restrict__ deg_i, int E)
{
    int i = blockIdx.x * 256 + threadIdx.x;
    if (i < E) atomicAdd(deg_i + dst[i], 1);
}

__global__ __launch_bounds__(256) void scanA_kernel(
    const int* __restrict__ deg_i, int* __restrict__ pos,
    int* __restrict__ bsum, int N)
{
    __shared__ int s[256];
    const int tid = threadIdx.x;
    const int i = blockIdx.x * 256 + tid;
    int v = (i < N) ? deg_i[i] : 0;
    s[tid] = v;
    __syncthreads();
    #pragma unroll
    for (int off = 1; off < 256; off <<= 1) {
        int t = (tid >= off) ? s[tid - off] : 0;
        __syncthreads();
        s[tid] += t;
        __syncthreads();
    }
    if (i < N) pos[i] = s[tid] - v;          // block-local exclusive
    if (tid == 255) bsum[blockIdx.x] = s[255];
}

__global__ __launch_bounds__(256) void scanB_kernel(int* __restrict__ bsum, int NB)
{
    __shared__ int s[256];
    const int tid = threadIdx.x;
    int v = (tid < NB) ? bsum[tid] : 0;
    s[tid] = v;
    __syncthreads();
    #pragma unroll
    for (int off = 1; off < 256; off <<= 1) {
        int t = (tid >= off) ? s[tid - off] : 0;
        __syncthreads();
        s[tid] += t;
        __syncthreads();
    }
    if (tid < NB) bsum[tid] = s[tid] - v;    // exclusive
}

__global__ __launch_bounds__(256) void scanC_kernel(
    int* __restrict__ pos, int* __restrict__ cursor,
    const int* __restrict__ bsum, int N)
{
    int i = blockIdx.x * 256 + threadIdx.x;
    if (i < N) {
        int p = pos[i] + bsum[blockIdx.x];
        pos[i] = p;
        cursor[i] = p;
    }
}

__global__ __launch_bounds__(256) void scatter_kernel(
    const int* __restrict__ dst, int* __restrict__ cursor,
    int2* __restrict__ sorted_ed, int E)
{
    int i = blockIdx.x * 256 + threadIdx.x;
    if (i < E) {
        int dv = dst[i];
        int slot = atomicAdd(cursor + dv, 1);
        sorted_ed[slot] = make_int2(i, dv);
    }
}

// ---------------------------------------------------------------------------
// efp_seg: process edges in dst-sorted order. Gather ef rows, MFMA -> efp
// (scatter-write to natural layout), and per-block segment column-sums into
// nb_sum (f32) with ~nseg*64 atomics per block.
// ---------------------------------------------------------------------------
__global__ __launch_bounds__(256) void efp_seg_kernel(
    const float* __restrict__ ef, const int2* __restrict__ sorted_ed,
    const ushort* __restrict__ Wt, ushort* __restrict__ efp,
    float* __restrict__ nb_sum, int E)
{
    __shared__ float Sf[64 * 68];   // f32 efp values, padded stride
    __shared__ int eids[64];
    __shared__ int dsts[64];
    const int tid = threadIdx.x;
    const long s0 = (long)blockIdx.x * 64;

    if (tid < 64) {
        long s = s0 + tid;
        int2 p2 = (s < E) ? sorted_ed[s] : make_int2(0, -1);
        eids[tid] = p2.x;
        dsts[tid] = p2.y;
    }
    __syncthreads();

    const int w = tid >> 6, lane = tid & 63;
    const int lr = lane & 15, g = lane >> 4;
    const int arow = 16 * w + lr;
    const long erow = eids[arow];

    const float4* ap = (const float4*)(ef + erow * D);
    float4 v0 = ap[2 * g], v1 = ap[2 * g + 1];
    float4 v2 = ap[8 + 2 * g], v3 = ap[8 + 2 * g + 1];
    short8 a0 = pack8(v0, v1), a1 = pack8(v2, v3);

    f32x4 acc[4];
    #pragma unroll
    for (int t = 0; t < 4; ++t) {
        f32x4 z = {0.f, 0.f, 0.f, 0.f};
        short8 b0 = *(const short8*)&Wt[(16 * t + lr) * D + 8 * g];
        short8 b1 = *(const short8*)&Wt[(16 * t + lr) * D + 32 + 8 * g];
        z = __builtin_amdgcn_mfma_f32_16x16x32_bf16(a0, b0, z, 0, 0, 0);
        z = __builtin_amdgcn_mfma_f32_16x16x32_bf16(a1, b1, z, 0, 0, 0);
        acc[t] = z;
    }

    // stash f32 values for segment sums
    #pragma unroll
    for (int t = 0; t < 4; ++t) {
        int c = 16 * t + lr;
        #pragma unroll
        for (int reg = 0; reg < 4; ++reg)
            Sf[(16 * w + 4 * g + reg) * 68 + c] = acc[t][reg];
    }

    // packed efp store (scattered to natural layout by eid)
    const bool odd = lane & 1;
    const int rb = 16 * w + 4 * g + (odd ? 2 : 0);
    long sl0 = s0 + rb, sl1 = s0 + rb + 1;
    long eo0 = (long)eids[rb] * D, eo1 = (long)eids[rb + 1] * D;
    #pragma unroll
    for (int t = 0; t < 4; ++t) {
        float p0 = __shfl_xor(acc[t][0], 1, 64);
        float p1 = __shfl_xor(acc[t][1], 1, 64);
        float p2 = __shfl_xor(acc[t][2], 1, 64);
        float p3 = __shfl_xor(acc[t][3], 1, 64);
        float lo0, hi0, lo1, hi1;
        if (odd) { lo0 = p2; hi0 = acc[t][2]; lo1 = p3; hi1 = acc[t][3]; }
        else     { lo0 = acc[t][0]; hi0 = p0; lo1 = acc[t][1]; hi1 = p1; }
        int cbase = 16 * t + (lr & ~1);
        unsigned dw0 = ((unsigned)f2b(hi0) << 16) | (unsigned)f2b(lo0);
        unsigned dw1 = ((unsigned)f2b(hi1) << 16) | (unsigned)f2b(lo1);
        if (sl0 < E) *(unsigned*)(efp + eo0 + cbase) = dw0;
        if (sl1 < E) *(unsigned*)(efp + eo1 + cbase) = dw1;
    }
    __syncthreads();

    // segment walk: one thread per column; dsts[] sorted within block.
    if (tid < 64) {
        const int col = tid;
        float seg = 0.f;
        int cur = dsts[0];
        for (int r = 0; r < 64; ++r) {
            int dv = dsts[r];
            if (dv != cur) {
                if (cur >= 0) atomicAdd(nb_sum + (long)cur * D + col, seg);
                seg = 0.f;
                cur = dv;
            }
            seg += Sf[r * 68 + col];
        }
        if (cur >= 0) atomicAdd(nb_sum + (long)cur * D + col, seg);
    }
}

// ---------------------------------------------------------------------------
// ndp_lite: ndp_b[n] = bf16( nb_sum[n]/max(deg,1) + nfp[n] ).  Elementwise.
// One thread per 8 columns.
// ---------------------------------------------------------------------------
__global__ __launch_bounds__(256) void ndp_lite_kernel(
    const float* __restrict__ nb_sum, const int* __restrict__ deg_i,
    const ushort* __restrict__ nfp_b, ushort* __restrict__ ndp_b, int N)
{
    long i = (long)blockIdx.x * 256 + threadIdx.x;   // group = (node, col-block)
    long node = i >> 3;
    int cb = (int)(i & 7);
    if (node >= N) return;
    float inv = 1.0f / fmaxf((float)deg_i[node], 1.0f);
    const float4* sp = (const float4*)(nb_sum + node * D + cb * 8);
    float4 x0 = sp[0], x1 = sp[1];
    short8 np = *(const short8*)(nfp_b + node * D + cb * 8);
    short8 r;
    r[0] = (short)f2b(x0.x * inv + b2f((ushort)np[0]));
    r[1] = (short)f2b(x0.y * inv + b2f((ushort)np[1]));
    r[2] = (short)f2b(x0.z * inv + b2f((ushort)np[2]));
    r[3] = (short)f2b(x0.w * inv + b2f((ushort)np[3]));
    r[4] = (short)f2b(x1.x * inv + b2f((ushort)np[4]));
    r[5] = (short)f2b(x1.y * inv + b2f((ushort)np[5]));
    r[6] = (short)f2b(x1.z * inv + b2f((ushort)np[6]));
    r[7] = (short)f2b(x1.w * inv + b2f((ushort)np[7]));
    *(short8*)(ndp_b + node * D + cb * 8) = r;
}

// ---------------------------------------------------------------------------
// final: ef_out = relu(efp + ndp[dst] + nfp[src] + bias2). Pure elementwise.
// 4 threads per edge, 16 cols each.
// ---------------------------------------------------------------------------
__global__ __launch_bounds__(256) void final_kernel(
    const ushort* __restrict__ efp, const int* __restrict__ src,
    const int* __restrict__ dst, const ushort* __restrict__ ndp_b,
    const ushort* __restrict__ nfp_b, const float* __restrict__ bias2,
    float* __restrict__ out, int E)
{
    long idx = (long)blockIdx.x * 256 + threadIdx.x;
    long e = idx >> 2;
    int q = (int)(idx & 3);
    if (e >= E) return;
    int dv = dst[e], sv = src[e];
    const short8* ep = (const short8*)(efp + e * D + q * 16);
    const short8* np = (const short8*)(ndp_b + (long)dv * D + q * 16);
    const short8* sp = (const short8*)(nfp_b + (long)sv * D + q * 16);
    short8 e0 = ep[0], e1 = ep[1];
    short8 n0 = np[0], n1 = np[1];
    short8 s0 = sp[0], s1 = sp[1];
    const float4* bp = (const float4*)(bias2 + q * 16);
    float4 b0 = bp[0], b1 = bp[1], b2 = bp[2], b3 = bp[3];

    float r[16];
    #pragma unroll
    for (int j = 0; j < 8; ++j) {
        r[j]     = b2f((ushort)e0[j]) + b2f((ushort)n0[j]) + b2f((ushort)s0[j]);
        r[8 + j] = b2f((ushort)e1[j]) + b2f((ushort)n1[j]) + b2f((ushort)s1[j]);
    }
    float4* op = (float4*)(out + e * D + q * 16);
    op[0] = make_float4(fmaxf(r[0] + b0.x, 0.f), fmaxf(r[1] + b0.y, 0.f),
                        fmaxf(r[2] + b0.z, 0.f), fmaxf(r[3] + b0.w, 0.f));
    op[1] = make_float4(fmaxf(r[4] + b1.x, 0.f), fmaxf(r[5] + b1.y, 0.f),
                        fmaxf(r[6] + b1.z, 0.f), fmaxf(r[7] + b1.w, 0.f));
    op[2] = make_float4(fmaxf(r[8] + b2.x, 0.f), fmaxf(r[9] + b2.y, 0.f),
                        fmaxf(r[10] + b2.z, 0.f), fmaxf(r[11] + b2.w, 0.f));
    op[3] = make_float4(fmaxf(r[12] + b3.x, 0.f), fmaxf(r[13] + b3.y, 0.f),
                        fmaxf(r[14] + b3.z, 0.f), fmaxf(r[15] + b3.w, 0.f));
}

// ---------------------------------------------------------------------------
extern "C" void kernel_launch(void* const* d_in, const int* in_sizes, int n_in,
                              void* d_out, int out_size, void* d_ws, size_t ws_size,
                              hipStream_t stream) {
    const float* nf        = (const float*)d_in[0];
    const float* ef        = (const float*)d_in[1];
    const int*   src       = (const int*)d_in[2];
    const int*   dst       = (const int*)d_in[3];
    const float* W_node    = (const float*)d_in[4];
    const float* W_edge    = (const float*)d_in[5];
    const float* bias_node = (const float*)d_in[6];
    const float* bias_edge = (const float*)d_in[7];
    const float* W_dense   = (const float*)d_in[8];
    const float* b_dense   = (const float*)d_in[9];

    const int N = in_sizes[0] / D;
    const int E = in_sizes[1] / D;
    const int NB = (N + 255) / 256;

    float* nf_out = (float*)d_out;
    float* ef_out = (float*)d_out + (size_t)N * D;

    // ws layout: [zeroed: deg_i, nb_sum] then the rest
    char* p = (char*)d_ws;
    int*    deg_i    = (int*)p;     p += (size_t)N * 4;           // zeroed
    float*  nb_sum   = (float*)p;   p += (size_t)N * D * 4;       // zeroed, 12.8 MB
    size_t  zbytes   = (size_t)(p - (char*)d_ws);
    int*    pos      = (int*)p;     p += (size_t)N * 4;
    int*    cursor   = (int*)p;     p += (size_t)N * 4;
    int*    bsum     = (int*)p;     p += 256 * 4;
    int2*   sorted_ed= (int2*)p;    p += (size_t)E * 8;           // 6.4 MB
    ushort* nfp_b    = (ushort*)p;  p += (size_t)N * D * 2;
    ushort* ndp_b    = (ushort*)p;  p += (size_t)N * D * 2;
    ushort* Wcomb_b  = (ushort*)p;  p += D * D * 2;
    float*  bias2    = (float*)p;   p += 256;
    ushort* efp      = (ushort*)p;  /* E*D*2 = 102.4 MB */

    hipMemsetAsync(d_ws, 0, zbytes, stream);

    setup_kernel<<<1, 256, 0, stream>>>(W_edge, W_dense, b_dense, bias_edge,
                                        Wcomb_b, bias2);
    node_proj_kernel<<<(N + 15) / 16, 256, 0, stream>>>(nf, W_node, bias_node,
                                                        W_dense + D * D, nf_out, nfp_b, N);
    hist_kernel<<<(E + 255) / 256, 256, 0, stream>>>(dst, deg_i, E);
    scanA_kernel<<<NB, 256, 0, stream>>>(deg_i, pos, bsum, N);
    scanB_kernel<<<1, 256, 0, stream>>>(bsum, NB);
    scanC_kernel<<<NB, 256, 0, stream>>>(pos, cursor, bsum, N);
    scatter_kernel<<<(E + 255) / 256, 256, 0, stream>>>(dst, cursor, sorted_ed, E);
    efp_seg_kernel<<<(E + 63) / 64, 256, 0, stream>>>(ef, sorted_ed, Wcomb_b,
                                                      efp, nb_sum, E);
    ndp_lite_kernel<<<(int)(((size_t)N * 8 + 255) / 256), 256, 0, stream>>>(
        nb_sum, deg_i, nfp_b, ndp_b, N);
    final_kernel<<<(int)(((size_t)E * 4 + 255) / 256), 256, 0, stream>>>(
        efp, src, dst, ndp_b, nfp_b, bias2, ef_out, E);
}

// Round 7
// 392.175 us; speedup vs baseline: 1.2166x; 1.0253x over previous
//
#include <hip/hip_runtime.h>

#define D 64

typedef __attribute__((ext_vector_type(8))) short short8;
typedef __attribute__((ext_vector_type(4))) float f32x4;

__device__ __forceinline__ ushort f2b(float f) {
    union { float f; unsigned u; } x; x.f = f;
    unsigned r = x.u + 0x7FFFu + ((x.u >> 16) & 1u);   // RNE to bf16
    return (ushort)(r >> 16);
}
__device__ __forceinline__ float b2f(ushort u) {
    union { float f; unsigned u; } x; x.u = ((unsigned)u) << 16;
    return x.f;
}
__device__ __forceinline__ short8 pack8(float4 a, float4 b) {
    short8 r;
    r[0] = (short)f2b(a.x); r[1] = (short)f2b(a.y); r[2] = (short)f2b(a.z); r[3] = (short)f2b(a.w);
    r[4] = (short)f2b(b.x); r[5] = (short)f2b(b.y); r[6] = (short)f2b(b.z); r[7] = (short)f2b(b.w);
    return r;
}

// ---------------------------------------------------------------------------
// Setup: Wcomb_b[n*64+k] = bf16( (W_edge @ W_dense[0:64])[k][n] ),
// bias2 = b_dense + bias_edge.
// ---------------------------------------------------------------------------
__global__ __launch_bounds__(256) void setup_kernel(
    const float* __restrict__ W_edge, const float* __restrict__ W_dense,
    const float* __restrict__ b_dense, const float* __restrict__ bias_edge,
    ushort* __restrict__ Wcomb_b, float* __restrict__ bias2)
{
    const int tid = threadIdx.x;
    for (int idx = tid; idx < D * D; idx += 256) {
        int k = idx >> 6, n = idx & 63;
        float s = 0.f;
        #pragma unroll 8
        for (int j = 0; j < D; ++j)
            s = fmaf(W_edge[k * D + j], W_dense[j * D + n], s);
        Wcomb_b[n * D + k] = f2b(s);   // B-fragment layout [n][k]
    }
    if (tid < D) bias2[tid] = b_dense[tid] + bias_edge[tid];
}

// ---------------------------------------------------------------------------
// Kernel 1 (fused): nf_out = relu(nf @ W_node + bias_node)  (f32, exact)
//                   nfp_b  = bf16( nf_out @ (0.5 * W_dense[64:128]) )
// ---------------------------------------------------------------------------
__global__ __launch_bounds__(256) void node_proj_kernel(
    const float* __restrict__ nf, const float* __restrict__ Wn,
    const float* __restrict__ bias, const float* __restrict__ Wd_bot,
    float* __restrict__ out, ushort* __restrict__ nfp_b, int N)
{
    constexpr int ROWS = 16;
    __shared__ float Ws[D * D];
    __shared__ float Wb[D * D];
    __shared__ float As[ROWS * D];
    __shared__ float Vs[ROWS * D];
    const int tid = threadIdx.x;
    const long row0 = (long)blockIdx.x * ROWS;

    #pragma unroll
    for (int i = tid; i < D * D / 4; i += 256) {
        ((float4*)Ws)[i] = ((const float4*)Wn)[i];
        float4 v = ((const float4*)Wd_bot)[i];
        ((float4*)Wb)[i] = make_float4(0.5f * v.x, 0.5f * v.y, 0.5f * v.z, 0.5f * v.w);
    }
    {
        int i = tid;  // ROWS*D/4 == 256
        long r = row0 + (i * 4) / D;
        ((float4*)As)[i] = (r < N) ? ((const float4*)nf)[row0 * D / 4 + i]
                                   : make_float4(0.f, 0.f, 0.f, 0.f);
    }
    __syncthreads();

    const int c = tid & 63;
    const float b = bias[c];
    for (int rr = tid >> 6; rr < ROWS; rr += 4) {
        float acc = 0.f;
        #pragma unroll
        for (int k = 0; k < D; ++k)
            acc = fmaf(As[rr * D + k], Ws[k * D + c], acc);
        float v = fmaxf(acc + b, 0.f);
        Vs[rr * D + c] = v;
        long r = row0 + rr;
        if (r < N) out[r * D + c] = v;
    }
    __syncthreads();
    for (int rr = tid >> 6; rr < ROWS; rr += 4) {
        float acc = 0.f;
        #pragma unroll
        for (int k = 0; k < D; ++k)
            acc = fmaf(Vs[rr * D + k], Wb[k * D + c], acc);
        long r = row0 + rr;
        if (r < N) nfp_b[r * D + c] = f2b(acc);
    }
}

// ---------------------------------------------------------------------------
// Counting sort of edges by dst: hist -> scan (3 stages) -> scatter (eid,dst)
// ---------------------------------------------------------------------------
__global__ __launch_bounds__(256) void hist_kernel(
    const int* __restrict__ dst, int* __restrict__ deg_i, int E)
{
    int i = blockIdx.x * 256 + threadIdx.x;
    if (i < E) atomicAdd(deg_i + dst[i], 1);
}

__global__ __launch_bounds__(256) void scanA_kernel(
    const int* __restrict__ deg_i, int* __restrict__ pos,
    int* __restrict__ bsum, int N)
{
    __shared__ int s[256];
    const int tid = threadIdx.x;
    const int i = blockIdx.x * 256 + tid;
    int v = (i < N) ? deg_i[i] : 0;
    s[tid] = v;
    __syncthreads();
    #pragma unroll
    for (int off = 1; off < 256; off <<= 1) {
        int t = (tid >= off) ? s[tid - off] : 0;
        __syncthreads();
        s[tid] += t;
        __syncthreads();
    }
    if (i < N) pos[i] = s[tid] - v;          // block-local exclusive
    if (tid == 255) bsum[blockIdx.x] = s[255];
}

__global__ __launch_bounds__(256) void scanB_kernel(int* __restrict__ bsum, int NB)
{
    __shared__ int s[256];
    const int tid = threadIdx.x;
    int v = (tid < NB) ? bsum[tid] : 0;
    s[tid] = v;
    __syncthreads();
    #pragma unroll
    for (int off = 1; off < 256; off <<= 1) {
        int t = (tid >= off) ? s[tid - off] : 0;
        __syncthreads();
        s[tid] += t;
        __syncthreads();
    }
    if (tid < NB) bsum[tid] = s[tid] - v;    // exclusive
}

__global__ __launch_bounds__(256) void scanC_kernel(
    int* __restrict__ pos, int* __restrict__ cursor,
    const int* __restrict__ bsum, int N)
{
    int i = blockIdx.x * 256 + threadIdx.x;
    if (i < N) {
        int p = pos[i] + bsum[blockIdx.x];
        pos[i] = p;
        cursor[i] = p;
    }
}

__global__ __launch_bounds__(256) void scatter_kernel(
    const int* __restrict__ dst, int* __restrict__ cursor,
    int2* __restrict__ sorted_ed, int E)
{
    int i = blockIdx.x * 256 + threadIdx.x;
    if (i < E) {
        int dv = dst[i];
        int slot = atomicAdd(cursor + dv, 1);
        sorted_ed[slot] = make_int2(i, dv);
    }
}

// ---------------------------------------------------------------------------
// efp_seg: process 128 edges (2 MFMA tiles) in dst-sorted order.
// Gather ef rows (all loads issued up front for MLP), MFMA -> efp (scattered
// packed stores to natural layout), then PARALLEL segment column-sums:
// each of 256 threads walks a 32-row strip for one column (runs crossing
// strip borders just emit extra atomics — order-agnostic f32 adds).
// ---------------------------------------------------------------------------
#define SEG_ROWS 128
__global__ __launch_bounds__(256) void efp_seg_kernel(
    const float* __restrict__ ef, const int2* __restrict__ sorted_ed,
    const ushort* __restrict__ Wt, ushort* __restrict__ efp,
    float* __restrict__ nb_sum, int E)
{
    __shared__ float Sf[SEG_ROWS * 68];   // 34816 B
    __shared__ int eids[SEG_ROWS];
    __shared__ int dsts[SEG_ROWS];
    const int tid = threadIdx.x;
    const long s0 = (long)blockIdx.x * SEG_ROWS;

    if (tid < SEG_ROWS) {
        long s = s0 + tid;
        int2 p2 = (s < E) ? sorted_ed[s] : make_int2(0, -1);
        eids[tid] = p2.x;
        dsts[tid] = p2.y;
    }
    __syncthreads();

    const int w = tid >> 6, lane = tid & 63;
    const int lr = lane & 15, g = lane >> 4;

    // Issue ALL ef-row gathers up front (8 float4 loads outstanding).
    float4 va[2][4];
    #pragma unroll
    for (int tt = 0; tt < 2; ++tt) {
        const long erow = eids[64 * tt + 16 * w + lr];
        const float4* ap = (const float4*)(ef + erow * D);
        va[tt][0] = ap[2 * g];     va[tt][1] = ap[2 * g + 1];
        va[tt][2] = ap[8 + 2 * g]; va[tt][3] = ap[8 + 2 * g + 1];
    }

    // B fragments: loaded once, reused for both tiles (L1-resident).
    short8 bf0[4], bf1[4];
    #pragma unroll
    for (int t = 0; t < 4; ++t) {
        bf0[t] = *(const short8*)&Wt[(16 * t + lr) * D + 8 * g];
        bf1[t] = *(const short8*)&Wt[(16 * t + lr) * D + 32 + 8 * g];
    }

    #pragma unroll
    for (int tt = 0; tt < 2; ++tt) {
        short8 a0 = pack8(va[tt][0], va[tt][1]);
        short8 a1 = pack8(va[tt][2], va[tt][3]);
        f32x4 acc[4];
        #pragma unroll
        for (int t = 0; t < 4; ++t) {
            f32x4 z = {0.f, 0.f, 0.f, 0.f};
            z = __builtin_amdgcn_mfma_f32_16x16x32_bf16(a0, bf0[t], z, 0, 0, 0);
            z = __builtin_amdgcn_mfma_f32_16x16x32_bf16(a1, bf1[t], z, 0, 0, 0);
            acc[t] = z;
        }

        // stash f32 values for segment sums
        #pragma unroll
        for (int t = 0; t < 4; ++t) {
            int c = 16 * t + lr;
            #pragma unroll
            for (int reg = 0; reg < 4; ++reg)
                Sf[(64 * tt + 16 * w + 4 * g + reg) * 68 + c] = acc[t][reg];
        }

        // packed efp store (scattered to natural layout by eid)
        const bool odd = lane & 1;
        const int rb = 64 * tt + 16 * w + 4 * g + (odd ? 2 : 0);
        long sl0 = s0 + rb, sl1 = s0 + rb + 1;
        long eo0 = (long)eids[rb] * D, eo1 = (long)eids[rb + 1] * D;
        #pragma unroll
        for (int t = 0; t < 4; ++t) {
            float p0 = __shfl_xor(acc[t][0], 1, 64);
            float p1 = __shfl_xor(acc[t][1], 1, 64);
            float p2 = __shfl_xor(acc[t][2], 1, 64);
            float p3 = __shfl_xor(acc[t][3], 1, 64);
            float lo0, hi0, lo1, hi1;
            if (odd) { lo0 = p2; hi0 = acc[t][2]; lo1 = p3; hi1 = acc[t][3]; }
            else     { lo0 = acc[t][0]; hi0 = p0; lo1 = acc[t][1]; hi1 = p1; }
            int cbase = 16 * t + (lr & ~1);
            unsigned dw0 = ((unsigned)f2b(hi0) << 16) | (unsigned)f2b(lo0);
            unsigned dw1 = ((unsigned)f2b(hi1) << 16) | (unsigned)f2b(lo1);
            if (sl0 < E) *(unsigned*)(efp + eo0 + cbase) = dw0;
            if (sl1 < E) *(unsigned*)(efp + eo1 + cbase) = dw1;
        }
    }
    __syncthreads();

    // parallel segment walk: col = tid&63, strip of 32 rows = tid>>6.
    {
        const int col = tid & 63;
        const int r0 = (tid >> 6) * 32;
        float seg = 0.f;
        int cur = dsts[r0];
        #pragma unroll 4
        for (int r = r0; r < r0 + 32; ++r) {
            int dv = dsts[r];
            if (dv != cur) {
                if (cur >= 0) atomicAdd(nb_sum + (long)cur * D + col, seg);
                seg = 0.f;
                cur = dv;
            }
            seg += Sf[r * 68 + col];
        }
        if (cur >= 0) atomicAdd(nb_sum + (long)cur * D + col, seg);
    }
}

// ---------------------------------------------------------------------------
// ndp_lite: ndp_b[n] = bf16( nb_sum[n]/max(deg,1) + nfp[n] ).  Elementwise.
// ---------------------------------------------------------------------------
__global__ __launch_bounds__(256) void ndp_lite_kernel(
    const float* __restrict__ nb_sum, const int* __restrict__ deg_i,
    const ushort* __restrict__ nfp_b, ushort* __restrict__ ndp_b, int N)
{
    long i = (long)blockIdx.x * 256 + threadIdx.x;   // group = (node, col-block)
    long node = i >> 3;
    int cb = (int)(i & 7);
    if (node >= N) return;
    float inv = 1.0f / fmaxf((float)deg_i[node], 1.0f);
    const float4* sp = (const float4*)(nb_sum + node * D + cb * 8);
    float4 x0 = sp[0], x1 = sp[1];
    short8 np = *(const short8*)(nfp_b + node * D + cb * 8);
    short8 r;
    r[0] = (short)f2b(x0.x * inv + b2f((ushort)np[0]));
    r[1] = (short)f2b(x0.y * inv + b2f((ushort)np[1]));
    r[2] = (short)f2b(x0.z * inv + b2f((ushort)np[2]));
    r[3] = (short)f2b(x0.w * inv + b2f((ushort)np[3]));
    r[4] = (short)f2b(x1.x * inv + b2f((ushort)np[4]));
    r[5] = (short)f2b(x1.y * inv + b2f((ushort)np[5]));
    r[6] = (short)f2b(x1.z * inv + b2f((ushort)np[6]));
    r[7] = (short)f2b(x1.w * inv + b2f((ushort)np[7]));
    *(short8*)(ndp_b + node * D + cb * 8) = r;
}

// ---------------------------------------------------------------------------
// final: ef_out = relu(efp + ndp[dst] + nfp[src] + bias2). Pure elementwise.
// 4 threads per edge, 16 cols each.
// ---------------------------------------------------------------------------
__global__ __launch_bounds__(256) void final_kernel(
    const ushort* __restrict__ efp, const int* __restrict__ src,
    const int* __restrict__ dst, const ushort* __restrict__ ndp_b,
    const ushort* __restrict__ nfp_b, const float* __restrict__ bias2,
    float* __restrict__ out, int E)
{
    long idx = (long)blockIdx.x * 256 + threadIdx.x;
    long e = idx >> 2;
    int q = (int)(idx & 3);
    if (e >= E) return;
    int dv = dst[e], sv = src[e];
    const short8* ep = (const short8*)(efp + e * D + q * 16);
    const short8* np = (const short8*)(ndp_b + (long)dv * D + q * 16);
    const short8* sp = (const short8*)(nfp_b + (long)sv * D + q * 16);
    short8 e0 = ep[0], e1 = ep[1];
    short8 n0 = np[0], n1 = np[1];
    short8 s0 = sp[0], s1 = sp[1];
    const float4* bp = (const float4*)(bias2 + q * 16);
    float4 b0 = bp[0], b1 = bp[1], b2 = bp[2], b3 = bp[3];

    float r[16];
    #pragma unroll
    for (int j = 0; j < 8; ++j) {
        r[j]     = b2f((ushort)e0[j]) + b2f((ushort)n0[j]) + b2f((ushort)s0[j]);
        r[8 + j] = b2f((ushort)e1[j]) + b2f((ushort)n1[j]) + b2f((ushort)s1[j]);
    }
    float4* op = (float4*)(out + e * D + q * 16);
    op[0] = make_float4(fmaxf(r[0] + b0.x, 0.f), fmaxf(r[1] + b0.y, 0.f),
                        fmaxf(r[2] + b0.z, 0.f), fmaxf(r[3] + b0.w, 0.f));
    op[1] = make_float4(fmaxf(r[4] + b1.x, 0.f), fmaxf(r[5] + b1.y, 0.f),
                        fmaxf(r[6] + b1.z, 0.f), fmaxf(r[7] + b1.w, 0.f));
    op[2] = make_float4(fmaxf(r[8] + b2.x, 0.f), fmaxf(r[9] + b2.y, 0.f),
                        fmaxf(r[10] + b2.z, 0.f), fmaxf(r[11] + b2.w, 0.f));
    op[3] = make_float4(fmaxf(r[12] + b3.x, 0.f), fmaxf(r[13] + b3.y, 0.f),
                        fmaxf(r[14] + b3.z, 0.f), fmaxf(r[15] + b3.w, 0.f));
}

// ---------------------------------------------------------------------------
extern "C" void kernel_launch(void* const* d_in, const int* in_sizes, int n_in,
                              void* d_out, int out_size, void* d_ws, size_t ws_size,
                              hipStream_t stream) {
    const float* nf        = (const float*)d_in[0];
    const float* ef        = (const float*)d_in[1];
    const int*   src       = (const int*)d_in[2];
    const int*   dst       = (const int*)d_in[3];
    const float* W_node    = (const float*)d_in[4];
    const float* W_edge    = (const float*)d_in[5];
    const float* bias_node = (const float*)d_in[6];
    const float* bias_edge = (const float*)d_in[7];
    const float* W_dense   = (const float*)d_in[8];
    const float* b_dense   = (const float*)d_in[9];

    const int N = in_sizes[0] / D;
    const int E = in_sizes[1] / D;
    const int NB = (N + 255) / 256;

    float* nf_out = (float*)d_out;
    float* ef_out = (float*)d_out + (size_t)N * D;

    // ws layout: [zeroed: deg_i, nb_sum] then the rest
    char* p = (char*)d_ws;
    int*    deg_i    = (int*)p;     p += (size_t)N * 4;           // zeroed
    float*  nb_sum   = (float*)p;   p += (size_t)N * D * 4;       // zeroed, 12.8 MB
    size_t  zbytes   = (size_t)(p - (char*)d_ws);
    int*    pos      = (int*)p;     p += (size_t)N * 4;
    int*    cursor   = (int*)p;     p += (size_t)N * 4;
    int*    bsum     = (int*)p;     p += 256 * 4;
    int2*   sorted_ed= (int2*)p;    p += (size_t)E * 8;           // 6.4 MB
    ushort* nfp_b    = (ushort*)p;  p += (size_t)N * D * 2;
    ushort* ndp_b    = (ushort*)p;  p += (size_t)N * D * 2;
    ushort* Wcomb_b  = (ushort*)p;  p += D * D * 2;
    float*  bias2    = (float*)p;   p += 256;
    ushort* efp      = (ushort*)p;  /* E*D*2 = 102.4 MB */

    hipMemsetAsync(d_ws, 0, zbytes, stream);

    setup_kernel<<<1, 256, 0, stream>>>(W_edge, W_dense, b_dense, bias_edge,
                                        Wcomb_b, bias2);
    node_proj_kernel<<<(N + 15) / 16, 256, 0, stream>>>(nf, W_node, bias_node,
                                                        W_dense + D * D, nf_out, nfp_b, N);
    hist_kernel<<<(E + 255) / 256, 256, 0, stream>>>(dst, deg_i, E);
    scanA_kernel<<<NB, 256, 0, stream>>>(deg_i, pos, bsum, N);
    scanB_kernel<<<1, 256, 0, stream>>>(bsum, NB);
    scanC_kernel<<<NB, 256, 0, stream>>>(pos, cursor, bsum, N);
    scatter_kernel<<<(E + 255) / 256, 256, 0, stream>>>(dst, cursor, sorted_ed, E);
    efp_seg_kernel<<<(E + SEG_ROWS - 1) / SEG_ROWS, 256, 0, stream>>>(
        ef, sorted_ed, Wcomb_b, efp, nb_sum, E);
    ndp_lite_kernel<<<(int)(((size_t)N * 8 + 255) / 256), 256, 0, stream>>>(
        nb_sum, deg_i, nfp_b, ndp_b, N);
    final_kernel<<<(int)(((size_t)E * 4 + 255) / 256), 256, 0, stream>>>(
        efp, src, dst, ndp_b, nfp_b, bias2, ef_out, E);
}